// Round 1
// baseline (2024.304 us; speedup 1.0000x reference)
//
#include <hip/hip_runtime.h>

// Problem constants (from reference)
constexpr int kB = 4;
constexpr int kT = 4096;
constexpr int kN_TOK = kB * kT;     // 16384 tokens (GEMM M)
constexpr int kH = 4096;            // hidden (GEMM N and K)
constexpr int kE = 4;               // experts
constexpr int kR = 8;               // LoRA rank
constexpr float kSCALE = 1.0f;      // ALPHA / RANK

typedef __bf16 bf16x8 __attribute__((ext_vector_type(8)));
typedef float  f32x4  __attribute__((ext_vector_type(4)));

// ---- helpers ---------------------------------------------------------------

__device__ inline unsigned short f2bf(float f) {
  union { float f; unsigned u; } v; v.f = f;
  unsigned r = v.u + 0x7FFFu + ((v.u >> 16) & 1u);   // round-to-nearest-even
  return (unsigned short)(r >> 16);
}

__device__ inline unsigned pack2(float lo, float hi) {
  return (unsigned)f2bf(lo) | ((unsigned)f2bf(hi) << 16);
}

// async 16B global -> LDS (global_load_lds_dwordx4); LDS dest must be
// wave-uniform base + lane*16, which our chunk mapping guarantees.
__device__ inline void gload_lds16(const unsigned short* g, unsigned short* l) {
  __builtin_amdgcn_global_load_lds(
      (const __attribute__((address_space(1))) unsigned int*)g,
      (__attribute__((address_space(3))) unsigned int*)l, 16, 0, 0);
}

// ---- kernel 1: W_up fp32 -> bf16 ------------------------------------------

__global__ __launch_bounds__(256) void convert_w_kernel(
    const float* __restrict__ w, unsigned short* __restrict__ wb) {
  size_t i = ((size_t)blockIdx.x * 256 + threadIdx.x) * 8;
  float4 a = *(const float4*)(w + i);
  float4 b = *(const float4*)(w + i + 4);
  uint4 s;
  s.x = pack2(a.x, a.y); s.y = pack2(a.z, a.w);
  s.z = pack2(b.x, b.y); s.w = pack2(b.z, b.w);
  *(uint4*)(wb + i) = s;
}

// ---- kernel 2: routing (fp64 logits) + LoRA z + x fp32->bf16 ---------------
// one block (256 threads) per token

__global__ __launch_bounds__(256) void route_kernel(
    const float* __restrict__ x, const float* __restrict__ gate_w,
    const float* __restrict__ ebias, const float* __restrict__ lora_A,
    unsigned short* __restrict__ xb, float* __restrict__ zbuf,
    int* __restrict__ top1) {
  const int n = blockIdx.x;
  const int t = threadIdx.x;
  const int lane = t & 63, wave = t >> 6;
  const float* xr = x + (size_t)n * kH;

  // load this thread's 16 elements (coalesced float4 x4)
  float4 xv[4];
#pragma unroll
  for (int k = 0; k < 4; ++k) xv[k] = *(const float4*)(xr + k * 1024 + t * 4);

  // write bf16 copy of x (coalesced 8B stores)
#pragma unroll
  for (int k = 0; k < 4; ++k) {
    uint2 p;
    p.x = pack2(xv[k].x, xv[k].y);
    p.y = pack2(xv[k].z, xv[k].w);
    *(uint2*)(xb + (size_t)n * kH + k * 1024 + t * 4) = p;
  }

  // gate logits, fp64 accumulate (argmax must match reference exactly)
  double g[kE] = {0.0, 0.0, 0.0, 0.0};
#pragma unroll
  for (int e = 0; e < kE; ++e) {
#pragma unroll
    for (int k = 0; k < 4; ++k) {
      float4 w = *(const float4*)(gate_w + (size_t)e * kH + k * 1024 + t * 4);
      g[e] += (double)xv[k].x * w.x + (double)xv[k].y * w.y +
              (double)xv[k].z * w.z + (double)xv[k].w * w.w;
    }
  }
#pragma unroll
  for (int e = 0; e < kE; ++e)
    for (int off = 32; off; off >>= 1) g[e] += __shfl_down(g[e], off, 64);

  __shared__ double gs[4][kE];
  __shared__ int se;
  if (lane == 0) {
#pragma unroll
    for (int e = 0; e < kE; ++e) gs[wave][e] = g[e];
  }
  __syncthreads();
  if (t == 0) {
    double best = -1e300; int bi = 0;
#pragma unroll
    for (int e = 0; e < kE; ++e) {
      double v = gs[0][e] + gs[1][e] + gs[2][e] + gs[3][e] + (double)ebias[e];
      if (v > best) { best = v; bi = e; }   // strict > keeps first index (np.argmax)
    }
    se = bi;
    top1[n] = bi;
  }
  __syncthreads();
  const int e = se;

  // z[n, r] = dot(x[n], lora_A[e, r, :])
  const float* Ae = lora_A + (size_t)e * kR * kH;
  float zr[kR] = {0, 0, 0, 0, 0, 0, 0, 0};
#pragma unroll
  for (int r = 0; r < kR; ++r) {
#pragma unroll
    for (int k = 0; k < 4; ++k) {
      float4 w = *(const float4*)(Ae + (size_t)r * kH + k * 1024 + t * 4);
      zr[r] += xv[k].x * w.x + xv[k].y * w.y + xv[k].z * w.z + xv[k].w * w.w;
    }
  }
#pragma unroll
  for (int r = 0; r < kR; ++r)
    for (int off = 32; off; off >>= 1) zr[r] += __shfl_down(zr[r], off, 64);

  __shared__ float zs[4][kR];
  if (lane == 0) {
#pragma unroll
    for (int r = 0; r < kR; ++r) zs[wave][r] = zr[r];
  }
  __syncthreads();
  if (t < kR) zbuf[(size_t)n * kR + t] = zs[0][t] + zs[1][t] + zs[2][t] + zs[3][t];
}

// ---- kernel 3: bf16 NT GEMM (m97 recipe) + fused LoRA epilogue -------------
// C[row, col] = sum_h xb[row,h]*wb[col,h]  + dot8(z[row], lora_B[e_row, col, :])
// 128x128 tile, 4 waves 2x2, BK=32, mfma_f32_16x16x32_bf16 4x4 tiles/wave.

__global__ __launch_bounds__(256) void gemm_kernel(
    const unsigned short* __restrict__ A,   // xb  [16384, 4096] bf16
    const unsigned short* __restrict__ Bw,  // wb  [4096, 4096] bf16
    const float* __restrict__ zbuf,         // [16384, 8]
    const int* __restrict__ top1,           // [16384]
    const float* __restrict__ loraB,        // [E, 4096, 8]
    float* __restrict__ out) {              // [16384, 4096] fp32
  constexpr int BK = 32;
  __shared__ unsigned short lsA[128 * BK];
  __shared__ unsigned short lsB[128 * BK];

  const int tid = threadIdx.x;
  const int lane = tid & 63;
  const int wave = tid >> 6;
  const int waveM = wave >> 1, waveN = wave & 1;
  const int lm = lane & 15, lq = lane >> 4;

  const int bm = blockIdx.x >> 5;   // 0..127  (M/128) — consecutive blocks share bm => A-tile L2 reuse
  const int bn = blockIdx.x & 31;   // 0..31   (N/128)

  const unsigned short* Abase = A + (size_t)(bm * 128) * kH;
  const unsigned short* Bbase = Bw + (size_t)(bn * 128) * kH;

  f32x4 acc[4][4];
#pragma unroll
  for (int mt = 0; mt < 4; ++mt)
#pragma unroll
    for (int nt = 0; nt < 4; ++nt) acc[mt][nt] = (f32x4)0.0f;

  for (int k0 = 0; k0 < kH; k0 += BK) {
    __syncthreads();   // previous iteration's reads done before overwrite
#pragma unroll
    for (int j = 0; j < 2; ++j) {
      int c = j * 256 + tid;            // 512 chunks of 16B per 8KB tile
      int row = c >> 2;
      int col = (c & 3) * 8;
      gload_lds16(Abase + (size_t)row * kH + k0 + col, &lsA[c * 8]);
      gload_lds16(Bbase + (size_t)row * kH + k0 + col, &lsB[c * 8]);
    }
    __syncthreads();   // compiler emits vmcnt(0) drain before barrier

    bf16x8 af[4], bf[4];
#pragma unroll
    for (int mt = 0; mt < 4; ++mt)
      af[mt] = *(const bf16x8*)&lsA[(waveM * 64 + mt * 16 + lm) * BK + lq * 8];
#pragma unroll
    for (int nt = 0; nt < 4; ++nt)
      bf[nt] = *(const bf16x8*)&lsB[(waveN * 64 + nt * 16 + lm) * BK + lq * 8];
#pragma unroll
    for (int mt = 0; mt < 4; ++mt)
#pragma unroll
      for (int nt = 0; nt < 4; ++nt)
        acc[mt][nt] = __builtin_amdgcn_mfma_f32_16x16x32_bf16(
            af[mt], bf[nt], acc[mt][nt], 0, 0, 0);
  }

  // epilogue: C/D layout col=lane&15, row=lq*4+reg  (m89/m91-verified)
  const int rowBase = bm * 128 + waveM * 64 + lq * 4;
  const int colBase = bn * 128 + waveN * 64 + lm;
#pragma unroll
  for (int mt = 0; mt < 4; ++mt) {
#pragma unroll
    for (int r = 0; r < 4; ++r) {
      const int row = rowBase + mt * 16 + r;
      const int e = top1[row];
      const float4 z0 = *(const float4*)(zbuf + (size_t)row * kR);
      const float4 z1 = *(const float4*)(zbuf + (size_t)row * kR + 4);
      const float* Bp = loraB + (size_t)e * kH * kR;
      float* orow = out + (size_t)row * kH;
#pragma unroll
      for (int nt = 0; nt < 4; ++nt) {
        const int col = colBase + nt * 16;
        const float4 b0 = *(const float4*)(Bp + (size_t)col * kR);
        const float4 b1 = *(const float4*)(Bp + (size_t)col * kR + 4);
        float d = z0.x * b0.x + z0.y * b0.y + z0.z * b0.z + z0.w * b0.w +
                  z1.x * b1.x + z1.y * b1.y + z1.z * b1.z + z1.w * b1.w;
        orow[col] = acc[mt][nt][r] + d * kSCALE;
      }
    }
  }
}

// ---- launch ----------------------------------------------------------------

extern "C" void kernel_launch(void* const* d_in, const int* in_sizes, int n_in,
                              void* d_out, int out_size, void* d_ws, size_t ws_size,
                              hipStream_t stream) {
  const float* x   = (const float*)d_in[0];   // [4,4096,4096]
  const float* Wup = (const float*)d_in[1];   // [4096,4096]
  const float* gw  = (const float*)d_in[2];   // [4,4096]
  const float* eb  = (const float*)d_in[3];   // [4]
  const float* lA  = (const float*)d_in[4];   // [4,8,4096]
  const float* lB  = (const float*)d_in[5];   // [4,4096,8]
  float* out = (float*)d_out;

  // workspace layout (bytes): wb 33554432 | xb 134217728 | z 524288 | top1 65536
  char* ws = (char*)d_ws;
  unsigned short* wb = (unsigned short*)ws;
  unsigned short* xb = (unsigned short*)(ws + 33554432);
  float* zbuf        = (float*)(ws + 33554432 + 134217728);
  int* top1          = (int*)(ws + 33554432 + 134217728 + 524288);

  convert_w_kernel<<<dim3((kH * kH) / (256 * 8)), dim3(256), 0, stream>>>(Wup, wb);
  route_kernel<<<dim3(kN_TOK), dim3(256), 0, stream>>>(x, gw, eb, lA, xb, zbuf, top1);
  gemm_kernel<<<dim3((kN_TOK / 128) * (kH / 128)), dim3(256), 0, stream>>>(
      xb, wb, zbuf, top1, lB, out);
}

// Round 2
// 1999.755 us; speedup vs baseline: 1.0123x; 1.0123x over previous
//
#include <hip/hip_runtime.h>

// Problem constants (from reference)
constexpr int kB = 4;
constexpr int kT = 4096;
constexpr int kN_TOK = kB * kT;     // 16384 tokens (GEMM M)
constexpr int kH = 4096;            // hidden (GEMM N and K)
constexpr int kE = 4;               // experts
constexpr int kR = 8;               // LoRA rank
constexpr float kSCALE = 1.0f;      // ALPHA / RANK

typedef __bf16 bf16x8 __attribute__((ext_vector_type(8)));
typedef float  f32x4  __attribute__((ext_vector_type(4)));

// ---- helpers ---------------------------------------------------------------

__device__ inline unsigned short f2bf(float f) {
  union { float f; unsigned u; } v; v.f = f;
  unsigned r = v.u + 0x7FFFu + ((v.u >> 16) & 1u);   // round-to-nearest-even
  return (unsigned short)(r >> 16);
}

__device__ inline unsigned pack2(float lo, float hi) {
  return (unsigned)f2bf(lo) | ((unsigned)f2bf(hi) << 16);
}

// async 16B global -> LDS (global_load_lds_dwordx4); LDS dest must be
// wave-uniform base + lane*16, which our chunk mapping guarantees.
__device__ inline void gload_lds16(const unsigned short* g, unsigned short* l) {
  __builtin_amdgcn_global_load_lds(
      (const __attribute__((address_space(1))) unsigned int*)g,
      (__attribute__((address_space(3))) unsigned int*)l, 16, 0, 0);
}

// ---- kernel 1: W_up fp32 -> bf16 ------------------------------------------

__global__ __launch_bounds__(256) void convert_w_kernel(
    const float* __restrict__ w, unsigned short* __restrict__ wb) {
  size_t i = ((size_t)blockIdx.x * 256 + threadIdx.x) * 8;
  float4 a = *(const float4*)(w + i);
  float4 b = *(const float4*)(w + i + 4);
  uint4 s;
  s.x = pack2(a.x, a.y); s.y = pack2(a.z, a.w);
  s.z = pack2(b.x, b.y); s.w = pack2(b.z, b.w);
  *(uint4*)(wb + i) = s;
}

// ---- kernel 2: routing + LoRA z + x fp32->bf16 -----------------------------
// one block (256 threads) per token. Gate: fp32 per-thread partial (16 terms,
// ~1e-6 rel err), fp64 cross-lane reduction -> argmax matches np reference.

__global__ __launch_bounds__(256) void route_kernel(
    const float* __restrict__ x, const float* __restrict__ gate_w,
    const float* __restrict__ ebias, const float* __restrict__ lora_A,
    unsigned short* __restrict__ xb, float* __restrict__ zbuf,
    int* __restrict__ top1) {
  const int n = blockIdx.x;
  const int t = threadIdx.x;
  const int lane = t & 63, wave = t >> 6;
  const float* xr = x + (size_t)n * kH;

  // load this thread's 16 elements (coalesced float4 x4)
  float4 xv[4];
#pragma unroll
  for (int k = 0; k < 4; ++k) xv[k] = *(const float4*)(xr + k * 1024 + t * 4);

  // write bf16 copy of x (coalesced 8B stores)
#pragma unroll
  for (int k = 0; k < 4; ++k) {
    uint2 p;
    p.x = pack2(xv[k].x, xv[k].y);
    p.y = pack2(xv[k].z, xv[k].w);
    *(uint2*)(xb + (size_t)n * kH + k * 1024 + t * 4) = p;
  }

  // gate logits
  double g[kE];
#pragma unroll
  for (int e = 0; e < kE; ++e) {
    float p = 0.f;
#pragma unroll
    for (int k = 0; k < 4; ++k) {
      float4 w = *(const float4*)(gate_w + (size_t)e * kH + k * 1024 + t * 4);
      p += xv[k].x * w.x + xv[k].y * w.y + xv[k].z * w.z + xv[k].w * w.w;
    }
    g[e] = (double)p;
  }
#pragma unroll
  for (int e = 0; e < kE; ++e)
    for (int off = 32; off; off >>= 1) g[e] += __shfl_down(g[e], off, 64);

  __shared__ double gs[4][kE];
  __shared__ int se;
  if (lane == 0) {
#pragma unroll
    for (int e = 0; e < kE; ++e) gs[wave][e] = g[e];
  }
  __syncthreads();
  if (t == 0) {
    double best = -1e300; int bi = 0;
#pragma unroll
    for (int e = 0; e < kE; ++e) {
      double v = gs[0][e] + gs[1][e] + gs[2][e] + gs[3][e] + (double)ebias[e];
      if (v > best) { best = v; bi = e; }   // strict > keeps first index (np.argmax)
    }
    se = bi;
    top1[n] = bi;
  }
  __syncthreads();
  const int e = se;

  // z[n, r] = dot(x[n], lora_A[e, r, :])
  const float* Ae = lora_A + (size_t)e * kR * kH;
  float zr[kR] = {0, 0, 0, 0, 0, 0, 0, 0};
#pragma unroll
  for (int r = 0; r < kR; ++r) {
#pragma unroll
    for (int k = 0; k < 4; ++k) {
      float4 w = *(const float4*)(Ae + (size_t)r * kH + k * 1024 + t * 4);
      zr[r] += xv[k].x * w.x + xv[k].y * w.y + xv[k].z * w.z + xv[k].w * w.w;
    }
  }
#pragma unroll
  for (int r = 0; r < kR; ++r)
    for (int off = 32; off; off >>= 1) zr[r] += __shfl_down(zr[r], off, 64);

  __shared__ float zs[4][kR];
  if (lane == 0) {
#pragma unroll
    for (int r = 0; r < kR; ++r) zs[wave][r] = zr[r];
  }
  __syncthreads();
  if (t < kR) zbuf[(size_t)n * kR + t] = zs[0][t] + zs[1][t] + zs[2][t] + zs[3][t];
}

// ---- kernel 3: bf16 NT GEMM (m97 recipe) + fused LoRA epilogue -------------
// C[row, col] = sum_h xb[row,h]*wb[col,h]  + dot8(z[row], lora_B[e_row, col, :])
// 128x128 tile, 4 waves 2x2, BK=32, mfma_f32_16x16x32_bf16 4x4 tiles/wave.
// XCD-aware swizzle: HW round-robins blockIdx%8 across XCDs, so each XCD owns
// a 4-wide bn strip (B footprint 4 MB -> per-XCD L2/L3 hot) and the 4 same-bm
// blocks on an XCD share one A-tile. A(128MB)+B(32MB) both fit the 256MB L3.

__global__ __launch_bounds__(256) void gemm_kernel(
    const unsigned short* __restrict__ A,   // xb  [16384, 4096] bf16
    const unsigned short* __restrict__ Bw,  // wb  [4096, 4096] bf16
    const float* __restrict__ zbuf,         // [16384, 8]
    const int* __restrict__ top1,           // [16384]
    const float* __restrict__ loraB,        // [E, 4096, 8]
    float* __restrict__ out) {              // [16384, 4096] fp32
  constexpr int BK = 32;
  __shared__ unsigned short lsA[128 * BK];
  __shared__ unsigned short lsB[128 * BK];

  const int tid = threadIdx.x;
  const int lane = tid & 63;
  const int wave = tid >> 6;
  const int waveM = wave >> 1, waveN = wave & 1;
  const int lm = lane & 15, lq = lane >> 4;

  // swizzle: id = xcd + 8*(bn_local + 4*bm); bijective over 4096 blocks
  const int id = blockIdx.x;
  const int xcd = id & 7;
  const int q = id >> 3;                 // 0..511
  const int bn = xcd * 4 + (q & 3);      // 0..31  (N/128)
  const int bm = q >> 2;                 // 0..127 (M/128)

  const unsigned short* Abase = A + (size_t)(bm * 128) * kH;
  const unsigned short* Bbase = Bw + (size_t)(bn * 128) * kH;

  f32x4 acc[4][4];
#pragma unroll
  for (int mt = 0; mt < 4; ++mt)
#pragma unroll
    for (int nt = 0; nt < 4; ++nt) acc[mt][nt] = (f32x4)0.0f;

  for (int k0 = 0; k0 < kH; k0 += BK) {
    __syncthreads();   // previous iteration's reads done before overwrite
#pragma unroll
    for (int j = 0; j < 2; ++j) {
      int c = j * 256 + tid;            // 512 chunks of 16B per 8KB tile
      int row = c >> 2;
      int col = (c & 3) * 8;
      gload_lds16(Abase + (size_t)row * kH + k0 + col, &lsA[c * 8]);
      gload_lds16(Bbase + (size_t)row * kH + k0 + col, &lsB[c * 8]);
    }
    __syncthreads();   // compiler emits vmcnt(0) drain before barrier

    bf16x8 af[4], bf[4];
#pragma unroll
    for (int mt = 0; mt < 4; ++mt)
      af[mt] = *(const bf16x8*)&lsA[(waveM * 64 + mt * 16 + lm) * BK + lq * 8];
#pragma unroll
    for (int nt = 0; nt < 4; ++nt)
      bf[nt] = *(const bf16x8*)&lsB[(waveN * 64 + nt * 16 + lm) * BK + lq * 8];
#pragma unroll
    for (int mt = 0; mt < 4; ++mt)
#pragma unroll
      for (int nt = 0; nt < 4; ++nt)
        acc[mt][nt] = __builtin_amdgcn_mfma_f32_16x16x32_bf16(
            af[mt], bf[nt], acc[mt][nt], 0, 0, 0);
  }

  // epilogue: C/D layout col=lane&15, row=lq*4+reg  (m89/m91-verified)
  const int rowBase = bm * 128 + waveM * 64 + lq * 4;
  const int colBase = bn * 128 + waveN * 64 + lm;
#pragma unroll
  for (int mt = 0; mt < 4; ++mt) {
#pragma unroll
    for (int r = 0; r < 4; ++r) {
      const int row = rowBase + mt * 16 + r;
      const int e = top1[row];
      const float4 z0 = *(const float4*)(zbuf + (size_t)row * kR);
      const float4 z1 = *(const float4*)(zbuf + (size_t)row * kR + 4);
      const float* Bp = loraB + (size_t)e * kH * kR;
      float* orow = out + (size_t)row * kH;
#pragma unroll
      for (int nt = 0; nt < 4; ++nt) {
        const int col = colBase + nt * 16;
        const float4 b0 = *(const float4*)(Bp + (size_t)col * kR);
        const float4 b1 = *(const float4*)(Bp + (size_t)col * kR + 4);
        float d = z0.x * b0.x + z0.y * b0.y + z0.z * b0.z + z0.w * b0.w +
                  z1.x * b1.x + z1.y * b1.y + z1.z * b1.z + z1.w * b1.w;
        orow[col] = acc[mt][nt][r] + d * kSCALE;
      }
    }
  }
}

// ---- launch ----------------------------------------------------------------

extern "C" void kernel_launch(void* const* d_in, const int* in_sizes, int n_in,
                              void* d_out, int out_size, void* d_ws, size_t ws_size,
                              hipStream_t stream) {
  const float* x   = (const float*)d_in[0];   // [4,4096,4096]
  const float* Wup = (const float*)d_in[1];   // [4096,4096]
  const float* gw  = (const float*)d_in[2];   // [4,4096]
  const float* eb  = (const float*)d_in[3];   // [4]
  const float* lA  = (const float*)d_in[4];   // [4,8,4096]
  const float* lB  = (const float*)d_in[5];   // [4,4096,8]
  float* out = (float*)d_out;

  // workspace layout (bytes): wb 33554432 | xb 134217728 | z 524288 | top1 65536
  char* ws = (char*)d_ws;
  unsigned short* wb = (unsigned short*)ws;
  unsigned short* xb = (unsigned short*)(ws + 33554432);
  float* zbuf        = (float*)(ws + 33554432 + 134217728);
  int* top1          = (int*)(ws + 33554432 + 134217728 + 524288);

  convert_w_kernel<<<dim3((kH * kH) / (256 * 8)), dim3(256), 0, stream>>>(Wup, wb);
  route_kernel<<<dim3(kN_TOK), dim3(256), 0, stream>>>(x, gw, eb, lA, xb, zbuf, top1);
  gemm_kernel<<<dim3((kN_TOK / 128) * (kH / 128)), dim3(256), 0, stream>>>(
      xb, wb, zbuf, top1, lB, out);
}